// Round 3
// baseline (52.376 us; speedup 1.0000x reference)
//
#include <hip/hip_runtime.h>
#include <hip/hip_bf16.h>

#define B_ 16
#define C_ 64
#define HW_ 4096              // H*W
#define K_ 1024
#define N_ 65536              // B*H*W pixels
#define NELEM 4194304         // B*C*H*W
#define NBLK 2048             // N_/32 : 32 pixels per block

typedef __attribute__((ext_vector_type(8))) short bf16x8;
typedef __attribute__((ext_vector_type(4))) float f32x4;

static __device__ __forceinline__ short f2bf(float f) {
    __hip_bfloat16 h = __float2bfloat16(f);           // RNE, native cvt on gfx950
    return (short)__builtin_bit_cast(unsigned short, h);
}

// ---- kernel 1: emb -> bf16 copy (coalesced) + codebook squared norms -----
// 32 blocks x 256 thr. ids 0..8191 each convert 8 consecutive emb elems;
// ids 0..1023 also compute e2[k].
__global__ __launch_bounds__(256) void vq_prep(const float* __restrict__ emb,
                                               float* __restrict__ e2,
                                               short* __restrict__ emb_bf) {
    const int id = blockIdx.x * 256 + threadIdx.x;
    {   // bf16 convert: 8 elems -> one 16B store
        const float4* src = (const float4*)(emb + (size_t)id * 8);
        float4 a = src[0], b = src[1];
        bf16x8 v;
        v[0]=f2bf(a.x); v[1]=f2bf(a.y); v[2]=f2bf(a.z); v[3]=f2bf(a.w);
        v[4]=f2bf(b.x); v[5]=f2bf(b.y); v[6]=f2bf(b.z); v[7]=f2bf(b.w);
        *(bf16x8*)(emb_bf + (size_t)id * 8) = v;
    }
    if (id < K_) {
        const float4* row = (const float4*)(emb + (size_t)id * C_);
        float s0 = 0.f, s1 = 0.f, s2 = 0.f, s3 = 0.f;
        #pragma unroll
        for (int i = 0; i < C_ / 4; ++i) {
            float4 v = row[i];
            s0 = fmaf(v.x, v.x, s0);
            s1 = fmaf(v.y, v.y, s1);
            s2 = fmaf(v.z, v.z, s2);
            s3 = fmaf(v.w, v.w, s3);
        }
        e2[id] = (s0 + s1) + (s2 + s3);
    }
}

// ---- kernel 2: fused MFMA argmin + gather + q_st + loss ------------------
// Block = 256 thr = 4 waves, owns 32 consecutive pixels (same b).
// Wave w scans K-quadrant [w*256, w*256+256) with mfma_f32_16x16x32_bf16:
//   A = 16-code tile from emb_bf (one dwordx4 per lane per half-K)
//   B = 16-pixel tile from z (converted in-register)
//   D[row=code=(l>>4)*4+r][col=pixel=l&15]   (m89-verified layout)
__global__ __launch_bounds__(256) void vq_main(const float* __restrict__ z,
                                               const float* __restrict__ emb,
                                               const short* __restrict__ emb_bf,
                                               const float* __restrict__ e2,
                                               float* __restrict__ out,
                                               float* __restrict__ psum) {
    __shared__ float sdist[4][32];
    __shared__ int   sidx[4][32];
    __shared__ int   cidx[32];
    __shared__ float red[4];

    const int tid  = threadIdx.x;
    const int lane = tid & 63;
    const int wave = __builtin_amdgcn_readfirstlane(tid >> 6);
    const int prow = lane & 15;        // pixel-in-tile / code-in-tile row
    const int kgrp = lane >> 4;        // k-group 0..3

    const int blk = blockIdx.x;        // 0..2047
    const int b   = blk >> 7;          // 128 blocks per image
    const int hw0 = (blk & 127) * 32;
    const float* zp = z + (size_t)b * C_ * HW_ + hw0;   // + c*HW_ + p

    // ---- z fragments (B operand): 2 pixel-tiles x 2 K-halves ----
    bf16x8 zf[2][2];
    #pragma unroll
    for (int pt = 0; pt < 2; ++pt) {
        const int p = pt * 16 + prow;
        #pragma unroll
        for (int ks = 0; ks < 2; ++ks) {
            const int d0 = ks * 32 + kgrp * 8;
            bf16x8 f;
            #pragma unroll
            for (int j = 0; j < 8; ++j)
                f[j] = f2bf(zp[(size_t)(d0 + j) * HW_ + p]);
            zf[pt][ks] = f;
        }
    }

    // ---- per-wave argmin over its 256-code quadrant ----
    const int kq = wave * 256;
    float best[2]  = {3.4e38f, 3.4e38f};
    int   bestk[2] = {kq, kq};

    for (int ct = 0; ct < 16; ++ct) {
        const int code_a = kq + ct * 16 + prow;           // A-frag row
        const short* er = emb_bf + (size_t)code_a * C_ + kgrp * 8;
        const bf16x8 af0 = *(const bf16x8*)er;
        const bf16x8 af1 = *(const bf16x8*)(er + 32);
        const int kcode = kq + ct * 16 + kgrp * 4;        // my 4 D-rows
        const float4 e2v = *(const float4*)(e2 + kcode);

        #pragma unroll
        for (int pt = 0; pt < 2; ++pt) {
            f32x4 acc = {0.f, 0.f, 0.f, 0.f};
            acc = __builtin_amdgcn_mfma_f32_16x16x32_bf16(af0, zf[pt][0], acc, 0, 0, 0);
            acc = __builtin_amdgcn_mfma_f32_16x16x32_bf16(af1, zf[pt][1], acc, 0, 0, 0);
            #pragma unroll
            for (int r = 0; r < 4; ++r) {
                const float e2r = (r == 0) ? e2v.x : (r == 1) ? e2v.y : (r == 2) ? e2v.z : e2v.w;
                const float dist = fmaf(-2.0f, acc[r], e2r);
                if (dist < best[pt]) { best[pt] = dist; bestk[pt] = kcode + r; }
            }
        }
    }

    // cross-lane combine over k-groups (bits 4,5 of lane)
    #pragma unroll
    for (int pt = 0; pt < 2; ++pt) {
        #pragma unroll
        for (int m = 16; m <= 32; m <<= 1) {
            const float od = __shfl_xor(best[pt], m);
            const int   ok = __shfl_xor(bestk[pt], m);
            if (od < best[pt] || (od == best[pt] && ok < bestk[pt])) {
                best[pt] = od; bestk[pt] = ok;
            }
        }
        if (kgrp == 0) {
            sdist[wave][pt * 16 + prow] = best[pt];
            sidx [wave][pt * 16 + prow] = bestk[pt];
        }
    }
    __syncthreads();

    // cross-wave combine (wave = ascending k quadrants)
    if (tid < 32) {
        float bb = sdist[0][tid];
        int   bi = sidx [0][tid];
        #pragma unroll
        for (int w2 = 1; w2 < 4; ++w2) {
            const float d = sdist[w2][tid];
            const int   k = sidx [w2][tid];
            if (d < bb || (d == bb && k < bi)) { bb = d; bi = k; }
        }
        cidx[tid] = bi;
    }
    __syncthreads();

    // ---- output phase: q_st = z + (q - z), partial loss ----
    float* op = out + (size_t)b * C_ * HW_ + hw0;
    const int p  = tid & 31;
    const int c0 = tid >> 5;                  // 0..7
    const float* qrow = emb + (size_t)cidx[p] * C_;
    float sq = 0.f;
    #pragma unroll
    for (int i = 0; i < 8; ++i) {
        const int c = c0 * 8 + i;
        const float zv   = zp[(size_t)c * HW_ + p];
        const float q    = qrow[c];
        const float diff = q - zv;            // matches reference op order
        op[(size_t)c * HW_ + p] = zv + diff;  // q_st = z + (q - z)
        sq = fmaf(diff, diff, sq);
    }
    #pragma unroll
    for (int off = 32; off; off >>= 1) sq += __shfl_xor(sq, off);
    if (lane == 0) red[wave] = sq;
    __syncthreads();
    if (tid == 0) psum[blk] = (red[0] + red[1]) + (red[2] + red[3]);
}

// ---- kernel 3: reduce partials -> loss -----------------------------------
__global__ __launch_bounds__(256) void vq_finalize(const float* __restrict__ psum,
                                                   float* __restrict__ out) {
    const int tid = threadIdx.x;
    float s = 0.f;
    #pragma unroll
    for (int i = 0; i < 8; ++i) s += psum[i * 256 + tid];
    #pragma unroll
    for (int off = 32; off; off >>= 1) s += __shfl_xor(s, off);
    __shared__ float red[4];
    if ((tid & 63) == 0) red[tid >> 6] = s;
    __syncthreads();
    if (tid == 0)
        out[NELEM] = 1.25f * ((red[0] + red[1]) + (red[2] + red[3])) / (float)NELEM;
}

extern "C" void kernel_launch(void* const* d_in, const int* in_sizes, int n_in,
                              void* d_out, int out_size, void* d_ws, size_t ws_size,
                              hipStream_t stream) {
    const float* z   = (const float*)d_in[0];   // [16,64,64,64]
    const float* emb = (const float*)d_in[1];   // [1024,64]
    float* out = (float*)d_out;                 // [4194304 q_st] ++ [1 loss]

    float* psum   = (float*)d_ws;               // 2048 floats
    float* e2     = psum + NBLK;                // 1024 floats
    short* emb_bf = (short*)(e2 + K_);          // 65536 bf16 (128 KB)

    vq_prep    <<<(K_ * C_) / (256 * 8), 256, 0, stream>>>(emb, e2, emb_bf);
    vq_main    <<<NBLK, 256, 0, stream>>>(z, emb, emb_bf, e2, out, psum);
    vq_finalize<<<1,    256, 0, stream>>>(psum, out);
}

// Round 4
// 35.385 us; speedup vs baseline: 1.4801x; 1.4801x over previous
//
#include <hip/hip_runtime.h>
#include <hip/hip_bf16.h>

#define B_ 16
#define C_ 64
#define HW_ 4096              // H*W
#define K_ 1024
#define N_ 65536              // B*H*W pixels
#define NELEM 4194304         // B*C*H*W
#define NBLK 1024             // N_/64 : 64 pixels per block

typedef __attribute__((ext_vector_type(8))) short bf16x8;
typedef __attribute__((ext_vector_type(4))) float f32x4;

static __device__ __forceinline__ short f2bf(float f) {
    __hip_bfloat16 h = __float2bfloat16(f);           // RNE, native cvt
    return (short)__builtin_bit_cast(unsigned short, h);
}

// ---- kernel 1: emb -> bf16(-2*emb) copy + e2' = 1 + |e|^2 ----------------
// 32 blocks x 256 thr. ids 0..8191 convert 8 consecutive emb elems;
// ids 0..1023 also compute e2'.
__global__ __launch_bounds__(256) void vq_prep(const float* __restrict__ emb,
                                               float* __restrict__ e2,
                                               short* __restrict__ emb_bf) {
    const int id = blockIdx.x * 256 + threadIdx.x;
    {   // -2x scale is exact in bf16 (sign + exponent shift)
        const float4* src = (const float4*)(emb + (size_t)id * 8);
        float4 a = src[0], b = src[1];
        bf16x8 v;
        v[0]=f2bf(-2.f*a.x); v[1]=f2bf(-2.f*a.y); v[2]=f2bf(-2.f*a.z); v[3]=f2bf(-2.f*a.w);
        v[4]=f2bf(-2.f*b.x); v[5]=f2bf(-2.f*b.y); v[6]=f2bf(-2.f*b.z); v[7]=f2bf(-2.f*b.w);
        *(bf16x8*)(emb_bf + (size_t)id * 8) = v;
    }
    if (id < K_) {
        const float4* row = (const float4*)(emb + (size_t)id * C_);
        float s0 = 0.f, s1 = 0.f, s2 = 0.f, s3 = 0.f;
        #pragma unroll
        for (int i = 0; i < C_ / 4; ++i) {
            float4 v = row[i];
            s0 = fmaf(v.x, v.x, s0);
            s1 = fmaf(v.y, v.y, s1);
            s2 = fmaf(v.z, v.z, s2);
            s3 = fmaf(v.w, v.w, s3);
        }
        e2[id] = 1.0f + ((s0 + s1) + (s2 + s3));   // keeps dist' > 0
    }
}

// ---- kernel 2: fused MFMA argmin + gather + q_st + loss ------------------
// Block = 256 thr = 4 waves, owns 64 consecutive pixels (same b).
// Wave w scans K-quadrant [w*256, w*256+256).
//   A = 16-code tile of (-2*emb) bf16; B = 16-pixel z tile; C-init = e2'
//   => D[row=code][col=pixel] = 1 + |e|^2 - 2 z.e  (strictly positive)
// Select: sortable int = (bits(dist) & ~1023) | k ; argmin = v_min_i32.
__global__ __launch_bounds__(256) void vq_main(const float* __restrict__ z,
                                               const float* __restrict__ emb,
                                               const short* __restrict__ emb_bf,
                                               const float* __restrict__ e2,
                                               float* __restrict__ out,
                                               float* __restrict__ psum) {
    __shared__ int   smin[4][64];
    __shared__ int   cidx[64];
    __shared__ float red[4];

    const int tid  = threadIdx.x;
    const int lane = tid & 63;
    const int wave = __builtin_amdgcn_readfirstlane(tid >> 6);
    const int prow = lane & 15;        // code-in-tile row / pixel-in-tile
    const int kgrp = lane >> 4;        // k-group 0..3

    const int blk = blockIdx.x;        // 0..1023
    const int b   = blk >> 6;          // 64 blocks per image
    const int hw0 = (blk & 63) * 64;
    const float* zp = z + (size_t)b * C_ * HW_ + hw0;   // + c*HW_ + p

    // ---- z fragments (B operand): 4 pixel-tiles x 2 K-halves ----
    bf16x8 zf[4][2];
    #pragma unroll
    for (int pt = 0; pt < 4; ++pt) {
        const int p = pt * 16 + prow;
        #pragma unroll
        for (int ks = 0; ks < 2; ++ks) {
            const int d0 = ks * 32 + kgrp * 8;
            bf16x8 f;
            #pragma unroll
            for (int j = 0; j < 8; ++j)
                f[j] = f2bf(zp[(size_t)(d0 + j) * HW_ + p]);
            zf[pt][ks] = f;
        }
    }

    // ---- per-wave argmin over its 256-code quadrant ----
    const int kq = wave * 256;
    int best[4] = {0x7FFFFFFF, 0x7FFFFFFF, 0x7FFFFFFF, 0x7FFFFFFF};

    #pragma unroll 4
    for (int ct = 0; ct < 16; ++ct) {
        const int code_a = kq + ct * 16 + prow;           // A-frag row
        const short* er = emb_bf + (size_t)code_a * C_ + kgrp * 8;
        const bf16x8 af0 = *(const bf16x8*)er;
        const bf16x8 af1 = *(const bf16x8*)(er + 32);
        const int kcode = kq + ct * 16 + kgrp * 4;        // my 4 D-rows
        const f32x4 e2v = *(const f32x4*)(e2 + kcode);    // acc init = e2'

        #pragma unroll
        for (int pt = 0; pt < 4; ++pt) {
            f32x4 acc = e2v;
            acc = __builtin_amdgcn_mfma_f32_16x16x32_bf16(af0, zf[pt][0], acc, 0, 0, 0);
            acc = __builtin_amdgcn_mfma_f32_16x16x32_bf16(af1, zf[pt][1], acc, 0, 0, 0);
            #pragma unroll
            for (int r = 0; r < 4; ++r) {
                const int s = (__builtin_bit_cast(int, acc[r]) & ~1023) | (kcode + r);
                best[pt] = min(best[pt], s);
            }
        }
    }

    // cross-lane combine over k-groups (bits 4,5 of lane)
    #pragma unroll
    for (int pt = 0; pt < 4; ++pt) {
        #pragma unroll
        for (int m = 16; m <= 32; m <<= 1)
            best[pt] = min(best[pt], __shfl_xor(best[pt], m));
        if (kgrp == 0) smin[wave][pt * 16 + prow] = best[pt];
    }
    __syncthreads();

    // cross-wave combine
    if (tid < 64) {
        int bb = min(min(smin[0][tid], smin[1][tid]),
                     min(smin[2][tid], smin[3][tid]));
        cidx[tid] = bb & 1023;
    }
    __syncthreads();

    // ---- output phase: q_st = z + (q - z), partial loss ----
    float* op = out + (size_t)b * C_ * HW_ + hw0;
    const int p  = tid & 63;
    const int c0 = tid >> 6;                  // 0..3
    const float* qrow = emb + (size_t)cidx[p] * C_;
    float sq = 0.f;
    #pragma unroll
    for (int i = 0; i < 16; ++i) {
        const int c = c0 * 16 + i;
        const float zv   = zp[(size_t)c * HW_ + p];
        const float q    = qrow[c];
        const float diff = q - zv;            // matches reference op order
        op[(size_t)c * HW_ + p] = zv + diff;  // q_st = z + (q - z)
        sq = fmaf(diff, diff, sq);
    }
    #pragma unroll
    for (int off = 32; off; off >>= 1) sq += __shfl_xor(sq, off);
    if (lane == 0) red[wave] = sq;
    __syncthreads();
    if (tid == 0) psum[blk] = (red[0] + red[1]) + (red[2] + red[3]);
}

// ---- kernel 3: reduce partials -> loss -----------------------------------
__global__ __launch_bounds__(256) void vq_finalize(const float* __restrict__ psum,
                                                   float* __restrict__ out) {
    const int tid = threadIdx.x;
    float s = 0.f;
    #pragma unroll
    for (int i = 0; i < 4; ++i) s += psum[i * 256 + tid];
    #pragma unroll
    for (int off = 32; off; off >>= 1) s += __shfl_xor(s, off);
    __shared__ float red[4];
    if ((tid & 63) == 0) red[tid >> 6] = s;
    __syncthreads();
    if (tid == 0)
        out[NELEM] = 1.25f * ((red[0] + red[1]) + (red[2] + red[3])) / (float)NELEM;
}

extern "C" void kernel_launch(void* const* d_in, const int* in_sizes, int n_in,
                              void* d_out, int out_size, void* d_ws, size_t ws_size,
                              hipStream_t stream) {
    const float* z   = (const float*)d_in[0];   // [16,64,64,64]
    const float* emb = (const float*)d_in[1];   // [1024,64]
    float* out = (float*)d_out;                 // [4194304 q_st] ++ [1 loss]

    float* psum   = (float*)d_ws;               // 1024 floats
    float* e2     = psum + K_;                  // 1024 floats (e2' = 1+|e|^2)
    short* emb_bf = (short*)(e2 + K_);          // 65536 bf16 of -2*emb

    vq_prep    <<<(K_ * C_) / (256 * 8), 256, 0, stream>>>(emb, e2, emb_bf);
    vq_main    <<<NBLK, 256, 0, stream>>>(z, emb, emb_bf, e2, out, psum);
    vq_finalize<<<1,    256, 0, stream>>>(psum, out);
}